// Round 13
// baseline (2696.369 us; speedup 1.0000x reference)
//
#include <hip/hip_runtime.h>
#include <hip/hip_bf16.h>

#define B_ 64
#define T_ 256
#define EMB_ 512
#define HID_ 1024
#define G4_ 4096
#define NCLS_ 32000
#define BH (B_ * HID_)

typedef _Float16 f16;
typedef _Float16 f16x8 __attribute__((ext_vector_type(8)));
typedef _Float16 f16x4 __attribute__((ext_vector_type(4)));
typedef float f32x4 __attribute__((ext_vector_type(4)));
typedef unsigned long long u64;

__device__ __forceinline__ float sigm(float x) { return 1.f / (1.f + __expf(-x)); }

// LLC/fabric-coherent (cross-XCD) accessors (R3..R12-proven).
__device__ __forceinline__ void stg_u64(u64* p, u64 v) {
  __hip_atomic_store(p, v, __ATOMIC_RELAXED, __HIP_MEMORY_SCOPE_AGENT);
}
__device__ __forceinline__ unsigned ldg_u32(const unsigned* p) {
  return __hip_atomic_load(p, __ATOMIC_RELAXED, __HIP_MEMORY_SCOPE_AGENT);
}
__device__ __forceinline__ void fadd_u32(unsigned* p) {
  __hip_atomic_fetch_add(p, 1u, __ATOMIC_RELAXED, __HIP_MEMORY_SCOPE_AGENT);
}

// ---------------- prep kernels ----------------

__global__ __launch_bounds__(256) void cvt_kernel(const float* __restrict__ src,
                                                  f16* __restrict__ dst, int n4) {
  int i = blockIdx.x * 256 + threadIdx.x;
  if (i < n4) {
    float4 v = ((const float4*)src)[i];
    f16x4 o = {(f16)v.x, (f16)v.y, (f16)v.z, (f16)v.w};
    *(f16x4*)(dst + (size_t)i * 4) = o;
  }
}

__global__ __launch_bounds__(256) void bsum_kernel(const float* __restrict__ a0,
                                                   const float* __restrict__ b0,
                                                   float* __restrict__ o0,
                                                   const float* __restrict__ a1,
                                                   const float* __restrict__ b1,
                                                   float* __restrict__ o1) {
  int i = blockIdx.x * 256 + threadIdx.x;
  if (i < G4_) {
    o0[i] = a0[i] + b0[i];
    o1[i] = a1[i] + b1[i];
  }
}

// x0 layout: [T][B][EMB] fp16 (row-major; cached, not on exchange path)
__global__ __launch_bounds__(128) void gather_kernel(const int* __restrict__ tokens,
                                                     const float* __restrict__ emb,
                                                     f16* __restrict__ x0) {
  int blk = blockIdx.x;  // t*64 + b
  int t = blk >> 6, b = blk & 63;
  int tok = tokens[b * T_ + t];
  float4 v = ((const float4*)(emb + (size_t)tok * EMB_))[threadIdx.x];
  f16x4 o = {(f16)v.x, (f16)v.y, (f16)v.z, (f16)v.w};
  *(f16x4*)(x0 + (size_t)blk * EMB_ + threadIdx.x * 4) = o;
}

// ---------------- wave-autonomous persistent recurrence kernel ----------------
// 4 independent chains: (layer, batch-half). Per block (256 thr = 4 waves):
// wave w = (half = w>>1, mi = w&1) handles batches half*32+mi*16 .. +15 with
// FULL K in-register (no cross-wave reduce, no __syncthreads in loop).
// Elementwise: gates exchanged in-wave via shfl_xor(8); c-state in VGPRs.
// h rings: blocked layout h[t][slice(128)][b(64)][u(8)] (R10-proven).
// Sync per chain: 8 sector counters (sector = slice>>4), per-wave fadd after
// vmcnt(0) drain; consumers poll 8 lines via lanes 0..7 (R9/R10-proven).
#define WAITW(CBASE, TGT)                                                   \
  {                                                                         \
    const unsigned tg_ = (TGT);                                             \
    unsigned v_ = tg_;                                                      \
    if (lane < 8) v_ = ldg_u32((CBASE) + lane * 32);                        \
    int it_ = 0;                                                            \
    while (!__all((int)(v_ >= tg_))) {                                      \
      if (++it_ > 4000000) break; /* safety valve: degrade, don't hang */   \
      __builtin_amdgcn_s_sleep(1);                                          \
      if (lane < 8) v_ = ldg_u32((CBASE) + lane * 32);                      \
    }                                                                       \
  }

__global__ __launch_bounds__(256, 1) void persist_kernel(
    const f16* __restrict__ x0, const f16* __restrict__ w0i,
    const f16* __restrict__ w0h, const f16* __restrict__ w1i,
    const f16* __restrict__ w1h, const float* __restrict__ b0s,
    const float* __restrict__ b1s, f16* __restrict__ h0r,
    f16* __restrict__ h1r, unsigned* flags) {
  __shared__ f16 Ws[32 * 2056];  // 131584 B: 32 rows x (Kcat + 8 pad)
  __shared__ f16 hws[4][128];    // 1 KB: per-wave h bounce (16 b x 8 u)

  const int layer = blockIdx.x >> 7;
  const int slice = blockIdx.x & 127;
  const int sector = slice >> 4;
  const int tid = threadIdx.x;
  const int lane = tid & 63, wave = tid >> 6;
  const int half = wave >> 1, mi = wave & 1;
  const int lr = lane & 15, lk = lane >> 4;
  const int j0 = slice * 8;
  const int bb = half * 32 + mi * 16;  // this wave's batch base

  const f16* whh = layer ? w1h : w0h;
  const f16* wih = layer ? w1i : w0i;
  const float* bs = layer ? b1s : b0s;
  f16* hown = layer ? h1r : h0r;
  const int KI = layer ? HID_ : EMB_;
  const int nch = (HID_ + KI) >> 3;  // uint4 chunks per row
  const int wstr = HID_ + KI + 8;    // 2056 / 1544

  // counters: chain = layer*2+half; 8 sectors x 128B lines each
  unsigned* ctr_own = flags + (layer * 2 + half) * 256;
  unsigned* ctr_l0h = flags + half * 256;  // layer0 same-half chain

  // ---- one-time: stage Wcat = [W_hh | W_ih] rows into LDS ----
  for (int r = wave * 8; r < wave * 8 + 8; ++r) {
    int grow = (r >> 3) * HID_ + j0 + (r & 7);  // gate*HID + unit
    for (int c = lane; c < nch; c += 64) {
      int kk = c * 8;
      const f16* src = (kk < HID_) ? (whh + (size_t)grow * HID_ + kk)
                                   : (wih + (size_t)grow * KI + (kk - HID_));
      *(uint4*)(Ws + r * wstr + kk) = *(const uint4*)src;
    }
  }
  // biases for this lane's unit u = lane&7
  float bi, bf, bg, bo;
  {
    int u = lane & 7;
    bi = bs[0 * HID_ + j0 + u];
    bf = bs[1 * HID_ + j0 + u];
    bg = bs[2 * HID_ + j0 + u];
    bo = bs[3 * HID_ + j0 + u];
  }
  __syncthreads();  // W ready (only block barrier in the kernel)

  const f16* wr0 = Ws + lr * wstr + lk * 8;
  const f16* wr1 = wr0 + 16 * wstr;

  // in-register cell state for this lane's two (b,u) pairs
  float cc0 = 0.f, cc1 = 0.f;
  const bool hi8 = (lane & 8) != 0;  // my batch-rows: hi8 ? regs {2,3} : {0,1}

  for (int s = 0; s < T_; ++s) {
    f32x4 acc0 = {}, acc1 = {};

    if (layer == 0) {
      // ---- x-part (no dependency; overlaps other chains' waits) ----
      const f16* xb = x0 + (size_t)s * (B_ * EMB_) + (size_t)(bb + lr) * EMB_ + lk * 8;
#pragma unroll
      for (int g = 0; g < 16; ++g) {
        f16x8 a = *(const f16x8*)(xb + g * 32);
        acc0 = __builtin_amdgcn_mfma_f32_16x16x32_f16(a, *(const f16x8*)(wr0 + (32 + g) * 32), acc0, 0, 0, 0);
        acc1 = __builtin_amdgcn_mfma_f32_16x16x32_f16(a, *(const f16x8*)(wr1 + (32 + g) * 32), acc1, 0, 0, 0);
      }
      // ---- wait own chain: h0[s-1] (slot s) ----
      WAITW(ctr_own, 32u * (unsigned)s)
      const f16* hb = h0r + (size_t)s * BH + (size_t)(bb + lr) * 8;
#pragma unroll 8
      for (int g = 0; g < 32; ++g) {
        f16x8 a = *(const f16x8*)(hb + (g * 4 + lk) * 512);
        acc0 = __builtin_amdgcn_mfma_f32_16x16x32_f16(a, *(const f16x8*)(wr0 + g * 32), acc0, 0, 0, 0);
        acc1 = __builtin_amdgcn_mfma_f32_16x16x32_f16(a, *(const f16x8*)(wr1 + g * 32), acc1, 0, 0, 0);
      }
    } else {
      // ---- wait layer0 same-half: h0[s] (slot s+1) done ----
      WAITW(ctr_l0h, 32u * (unsigned)(s + 1))
      const f16* xb = h0r + (size_t)(s + 1) * BH + (size_t)(bb + lr) * 8;
#pragma unroll 8
      for (int g = 0; g < 32; ++g) {
        f16x8 a = *(const f16x8*)(xb + (g * 4 + lk) * 512);
        acc0 = __builtin_amdgcn_mfma_f32_16x16x32_f16(a, *(const f16x8*)(wr0 + (32 + g) * 32), acc0, 0, 0, 0);
        acc1 = __builtin_amdgcn_mfma_f32_16x16x32_f16(a, *(const f16x8*)(wr1 + (32 + g) * 32), acc1, 0, 0, 0);
      }
      // ---- wait own chain: h1[s-1] (slot s) ----
      WAITW(ctr_own, 32u * (unsigned)s)
      const f16* hb = h1r + (size_t)s * BH + (size_t)(bb + lr) * 8;
#pragma unroll 8
      for (int g = 0; g < 32; ++g) {
        f16x8 a = *(const f16x8*)(hb + (g * 4 + lk) * 512);
        acc0 = __builtin_amdgcn_mfma_f32_16x16x32_f16(a, *(const f16x8*)(wr0 + g * 32), acc0, 0, 0, 0);
        acc1 = __builtin_amdgcn_mfma_f32_16x16x32_f16(a, *(const f16x8*)(wr1 + g * 32), acc1, 0, 0, 0);
      }
    }

    // ---- in-wave elementwise ----
    // C layout: col=lane&15, row=(lane>>4)*4+reg. Block rows: g*8+u (g=gate).
    // acc0 cols: u (g0) / 8+u (g1); acc1 cols: u (g2) / 8+u (g3).
    // Lane pair (L, L^8) exchanges the complementary gates for same u.
    {
      float oA0 = hi8 ? acc0[2] : acc0[0];  // own gates, my row 0
      float oA1 = hi8 ? acc0[3] : acc0[1];
      float oB0 = hi8 ? acc1[2] : acc1[0];
      float oB1 = hi8 ? acc1[3] : acc1[1];
      float sA0 = hi8 ? acc0[0] : acc0[2];  // what partner needs
      float sA1 = hi8 ? acc0[1] : acc0[3];
      float sB0 = hi8 ? acc1[0] : acc1[2];
      float sB1 = hi8 ? acc1[1] : acc1[3];
      float rA0 = __shfl_xor(sA0, 8);
      float rA1 = __shfl_xor(sA1, 8);
      float rB0 = __shfl_xor(sB0, 8);
      float rB1 = __shfl_xor(sB1, 8);
      // lane with col<8 (hi8==false): own=g0(acc0),g2(acc1); recv=g1,g3.
      float pi0 = (!hi8 ? oA0 : rA0) + bi, pf0 = (!hi8 ? rA0 : oA0) + bf;
      float pg0 = (!hi8 ? oB0 : rB0) + bg, po0 = (!hi8 ? rB0 : oB0) + bo;
      float pi1 = (!hi8 ? oA1 : rA1) + bi, pf1 = (!hi8 ? rA1 : oA1) + bf;
      float pg1 = (!hi8 ? oB1 : rB1) + bg, po1 = (!hi8 ? rB1 : oB1) + bo;
      float ig0 = sigm(pi0), fg0 = sigm(pf0), gg0 = tanhf(pg0), og0 = sigm(po0);
      float ig1 = sigm(pi1), fg1 = sigm(pf1), gg1 = tanhf(pg1), og1 = sigm(po1);
      cc0 = fg0 * cc0 + ig0 * gg0;
      cc1 = fg1 * cc1 + ig1 * gg1;
      f16 h0v = (f16)(og0 * tanhf(cc0));
      f16 h1v = (f16)(og1 * tanhf(cc1));
      int u = lane & 7;
      int row0 = (lane >> 4) * 4 + (hi8 ? 2 : 0);  // local batch row of h0v
      hws[wave][row0 * 8 + u] = h0v;
      hws[wave][(row0 + 1) * 8 + u] = h1v;
    }
    asm volatile("s_waitcnt lgkmcnt(0)" ::: "memory");
    // coalesced 256 B store of this wave's h tile (agent scope)
    if (lane < 32) {
      u64 v = *(const u64*)(&hws[wave][lane * 4]);
      stg_u64((u64*)(hown + (size_t)(s + 1) * BH + slice * 512 + bb * 8 + lane * 4), v);
    }
    // ---- publish: drain stores, then per-wave arrival add ----
    asm volatile("s_waitcnt vmcnt(0)" ::: "memory");
    if (lane == 0) fadd_u32(&ctr_own[sector * 32]);
  }
}

// ---------------- FC kernel: out = h1_last @ fc_w^T + fc_b ----------------
// A (h1[256]) is in blocked layout: (b, k) at ((k>>3)*64 + b)*8 + (k&7).
__global__ __launch_bounds__(256) void fc_kernel(const f16* __restrict__ A,
                                                 const float* __restrict__ fcw,
                                                 const float* __restrict__ fcb,
                                                 float* __restrict__ out) {
  const int n0 = blockIdx.x * 64;
  __shared__ char smem[18432];
  f16* As = (f16*)smem;
  f16* Bs = (f16*)(smem + 9216);
  const int tid = threadIdx.x;
  const int lane = tid & 63, wave = tid >> 6;
  const int wm = wave & 1, wn = wave >> 1;
  const int lr = lane & 15, lk = lane >> 4;
  f32x4 acc[2][2] = {};

  for (int kt = 0; kt < HID_ / 64; ++kt) {
    const int k0 = kt * 64;
    __syncthreads();
#pragma unroll
    for (int i = 0; i < 2; ++i) {
      int id = tid + 256 * i;
      int r = id >> 3, c8 = id & 7;
      uint4 av = *(const uint4*)(A + (size_t)((k0 >> 3) + c8) * 512 + r * 8);
      *(uint4*)(As + r * 72 + c8 * 8) = av;
    }
#pragma unroll
    for (int i = 0; i < 4; ++i) {
      int id = tid + 256 * i;
      int r = id >> 4, c4 = id & 15;
      float4 v = *(const float4*)(fcw + (size_t)(n0 + r) * HID_ + k0 + c4 * 4);
      f16x4 o = {(f16)v.x, (f16)v.y, (f16)v.z, (f16)v.w};
      *(f16x4*)(Bs + r * 72 + c4 * 4) = o;
    }
    __syncthreads();
#pragma unroll
    for (int ks = 0; ks < 2; ++ks) {
      f16x8 a0 = *(const f16x8*)(As + (wm * 32 + lr) * 72 + ks * 32 + lk * 8);
      f16x8 a1 = *(const f16x8*)(As + (wm * 32 + 16 + lr) * 72 + ks * 32 + lk * 8);
      f16x8 b0 = *(const f16x8*)(Bs + (wn * 32 + lr) * 72 + ks * 32 + lk * 8);
      f16x8 b1 = *(const f16x8*)(Bs + (wn * 32 + 16 + lr) * 72 + ks * 32 + lk * 8);
      acc[0][0] = __builtin_amdgcn_mfma_f32_16x16x32_f16(a0, b0, acc[0][0], 0, 0, 0);
      acc[0][1] = __builtin_amdgcn_mfma_f32_16x16x32_f16(a0, b1, acc[0][1], 0, 0, 0);
      acc[1][0] = __builtin_amdgcn_mfma_f32_16x16x32_f16(a1, b0, acc[1][0], 0, 0, 0);
      acc[1][1] = __builtin_amdgcn_mfma_f32_16x16x32_f16(a1, b1, acc[1][1], 0, 0, 0);
    }
  }

#pragma unroll
  for (int mf = 0; mf < 2; ++mf)
#pragma unroll
    for (int nf = 0; nf < 2; ++nf) {
      int n = n0 + wn * 32 + nf * 16 + lr;
      float bias = fcb[n];
      int bbase = wm * 32 + mf * 16 + lk * 4;
#pragma unroll
      for (int rg = 0; rg < 4; ++rg)
        out[(size_t)(bbase + rg) * NCLS_ + n] = acc[mf][nf][rg] + bias;
    }
}

// ---------------- launch ----------------

extern "C" void kernel_launch(void* const* d_in, const int* in_sizes, int n_in,
                              void* d_out, int out_size, void* d_ws,
                              size_t ws_size, hipStream_t stream) {
  const int* tokens = (const int*)d_in[0];
  const float* emb = (const float*)d_in[1];
  const float* W_ih0 = (const float*)d_in[2];
  const float* W_hh0 = (const float*)d_in[3];
  const float* b_ih0 = (const float*)d_in[4];
  const float* b_hh0 = (const float*)d_in[5];
  const float* W_ih1 = (const float*)d_in[6];
  const float* W_hh1 = (const float*)d_in[7];
  const float* b_ih1 = (const float*)d_in[8];
  const float* b_hh1 = (const float*)d_in[9];
  const float* fc_w = (const float*)d_in[10];
  const float* fc_b = (const float*)d_in[11];
  float* out = (float*)d_out;

  char* ws = (char*)d_ws;
  size_t off = 0;
  auto carve = [&](size_t bytes) -> char* {
    char* p = ws + off;
    off += (bytes + 255) & ~(size_t)255;
    return p;
  };
  f16* w0i = (f16*)carve((size_t)G4_ * EMB_ * 2);
  f16* w0h = (f16*)carve((size_t)G4_ * HID_ * 2);
  f16* w1i = (f16*)carve((size_t)G4_ * HID_ * 2);
  f16* w1h = (f16*)carve((size_t)G4_ * HID_ * 2);
  f16* x0 = (f16*)carve((size_t)T_ * B_ * EMB_ * 2);
  float* b0s = (float*)carve(G4_ * 4);
  float* b1s = (float*)carve(G4_ * 4);
  f16* h0r = (f16*)carve(257ull * BH * 2);  // blocked: [t][slice][b][u8]
  f16* h1r = (f16*)carve(257ull * BH * 2);
  unsigned* flags = (unsigned*)carve(1024 * 4);  // 4 chains x 8 sectors x 128B

  hipMemsetAsync(flags, 0, 1024 * 4, stream);
  hipMemsetAsync(h0r, 0, (size_t)BH * 2, stream);
  hipMemsetAsync(h1r, 0, (size_t)BH * 2, stream);

  cvt_kernel<<<(G4_ * EMB_ / 4 + 255) / 256, 256, 0, stream>>>(W_ih0, w0i, G4_ * EMB_ / 4);
  cvt_kernel<<<(G4_ * HID_ / 4 + 255) / 256, 256, 0, stream>>>(W_hh0, w0h, G4_ * HID_ / 4);
  cvt_kernel<<<(G4_ * HID_ / 4 + 255) / 256, 256, 0, stream>>>(W_ih1, w1i, G4_ * HID_ / 4);
  cvt_kernel<<<(G4_ * HID_ / 4 + 255) / 256, 256, 0, stream>>>(W_hh1, w1h, G4_ * HID_ / 4);
  bsum_kernel<<<(G4_ + 255) / 256, 256, 0, stream>>>(b_ih0, b_hh0, b0s, b_ih1, b_hh1, b1s);
  gather_kernel<<<T_ * B_, 128, 0, stream>>>(tokens, emb, x0);

  persist_kernel<<<256, 256, 0, stream>>>(x0, w0i, w0h, w1i, w1h, b0s, b1s,
                                          h0r, h1r, flags);

  fc_kernel<<<NCLS_ / 64, 256, 0, stream>>>(h1r + 256ull * BH, fc_w, fc_b, out);
}